// Round 1
// baseline (39509.140 us; speedup 1.0000x reference)
//
#include <hip/hip_runtime.h>

#define NN 50000
#define NE 1600000
#define NGR 64
#define XD 32
#define HID 128
#define NF 128
#define NG 50
#define GD 16
#define NL 6
#define SH 64
#define EPSF 1e-5f

// ---------------- node encoder pass 1: t = x@We1 + be1, accumulate col stats
__global__ __launch_bounds__(256) void k_enc1(const float* __restrict__ x,
    const float* __restrict__ We1, const float* __restrict__ be1,
    float* __restrict__ t, float* __restrict__ stats) {
  int c = threadIdx.x & 127;
  int half = threadIdx.x >> 7;
  float b = be1[c];
  float psum = 0.f, psq = 0.f;
  for (int n = blockIdx.x * 2 + half; n < NN; n += gridDim.x * 2) {
    const float* xr = x + (size_t)n * XD;
    float v = b;
#pragma unroll
    for (int k = 0; k < XD; ++k) v = fmaf(xr[k], We1[k * HID + c], v);
    t[(size_t)n * HID + c] = v;
    psum += v; psq += v * v;
  }
  __shared__ float s0[256], s1[256];
  s0[threadIdx.x] = psum; s1[threadIdx.x] = psq;
  __syncthreads();
  if (threadIdx.x < 128) {
    atomicAdd(&stats[threadIdx.x], s0[threadIdx.x] + s0[threadIdx.x + 128]);
    atomicAdd(&stats[128 + threadIdx.x], s1[threadIdx.x] + s1[threadIdx.x + 128]);
  }
}

// ---------------- BN finalize: a = g*rsqrt(var+eps); b = beta - mean*a
__global__ __launch_bounds__(128) void k_bn_fin(const float* __restrict__ gamma,
    const float* __restrict__ beta, float* __restrict__ stats, int C, float invn) {
  int c = threadIdx.x;
  if (c < C) {
    float mean = stats[c] * invn;
    float var = stats[128 + c] * invn - mean * mean;
    float a = gamma[c] * rsqrtf(var + EPSF);
    stats[256 + c] = a;
    stats[384 + c] = beta[c] - mean * a;
  }
}

// ---------------- node encoder pass 2: h = relu(bn(t)) @ We2 + be2
__global__ __launch_bounds__(128) void k_enc2(const float* __restrict__ t,
    const float* __restrict__ stats, const float* __restrict__ We2,
    const float* __restrict__ be2, float* __restrict__ h) {
  __shared__ float r[HID];
  int c = threadIdx.x;
  float a = stats[256 + c], b = stats[384 + c];
  float bias = be2[c];
  for (int n = blockIdx.x; n < NN; n += gridDim.x) {
    float v = fmaf(t[(size_t)n * HID + c], a, b);
    r[c] = fmaxf(v, 0.f);
    __syncthreads();
    float acc = bias;
#pragma unroll 8
    for (int k = 0; k < HID; ++k) acc = fmaf(r[k], We2[k * HID + c], acc);
    h[(size_t)n * HID + c] = acc;
    __syncthreads();
  }
}

// ---------------- gaussian smearing: ea[e][g] = exp(coeff*(d-off_g)^2)
__global__ __launch_bounds__(256) void k_smear(const float* __restrict__ eattr,
    float* __restrict__ ea) {
  int idx = blockIdx.x * 256 + threadIdx.x;  // < NE*NG = 80e6 < 2^31
  if (idx >= NE * NG) return;
  int e = idx / NG;
  int g = idx - e * NG;
  float ax = eattr[(size_t)e * 3], ay = eattr[(size_t)e * 3 + 1], az = eattr[(size_t)e * 3 + 2];
  float d = sqrtf(ax * ax + ay * ay + az * az);
  float off = (10.0f / 49.0f) * (float)g;
  float z = d - off;
  ea[idx] = __expf(-12.005f * z * z);
}

// ---------------- per-layer edge kernel: W = relu(ea@Wf1+bf1)@Wf2+bf2;
//                  msg = h[row]*W; atomicAdd agg[col]
__global__ __launch_bounds__(256) void k_edge(
    const float* __restrict__ ea, const float* __restrict__ h,
    const int* __restrict__ row, const int* __restrict__ col,
    const float* __restrict__ Wf1, const float* __restrict__ bf1,
    const float* __restrict__ Wf2, const float* __restrict__ bf2,
    float* __restrict__ agg) {
  __shared__ float ea_s[16][NG + 2];
  __shared__ float f1_s[16][NF];
  const int ce = threadIdx.x & 31;
  const int eg = threadIdx.x >> 5;
  const int c0 = ce * 4;
  const int e0 = eg * 2, e1 = e0 + 1;
  for (int tile = blockIdx.x; tile < NE / 16; tile += gridDim.x) {
    const int eb = tile * 16;
    for (int i = threadIdx.x; i < 16 * NG; i += 256) {
      int le = i / NG, g = i - le * NG;
      ea_s[le][g] = ea[(size_t)(eb + le) * NG + g];
    }
    __syncthreads();
    float a0[4], a1[4];
#pragma unroll
    for (int j = 0; j < 4; ++j) { a0[j] = bf1[c0 + j]; a1[j] = a0[j]; }
    for (int g = 0; g < NG; ++g) {
      float x0 = ea_s[e0][g], x1 = ea_s[e1][g];
      float4 w = *(const float4*)(Wf1 + (size_t)g * NF + c0);
      a0[0] = fmaf(x0, w.x, a0[0]); a0[1] = fmaf(x0, w.y, a0[1]);
      a0[2] = fmaf(x0, w.z, a0[2]); a0[3] = fmaf(x0, w.w, a0[3]);
      a1[0] = fmaf(x1, w.x, a1[0]); a1[1] = fmaf(x1, w.y, a1[1]);
      a1[2] = fmaf(x1, w.z, a1[2]); a1[3] = fmaf(x1, w.w, a1[3]);
    }
#pragma unroll
    for (int j = 0; j < 4; ++j) {
      f1_s[e0][c0 + j] = fmaxf(a0[j], 0.f);
      f1_s[e1][c0 + j] = fmaxf(a1[j], 0.f);
    }
    __syncthreads();
#pragma unroll
    for (int j = 0; j < 4; ++j) { a0[j] = bf2[c0 + j]; a1[j] = a0[j]; }
    for (int k = 0; k < NF; ++k) {
      float x0 = f1_s[e0][k], x1 = f1_s[e1][k];
      float4 w = *(const float4*)(Wf2 + (size_t)k * NF + c0);
      a0[0] = fmaf(x0, w.x, a0[0]); a0[1] = fmaf(x0, w.y, a0[1]);
      a0[2] = fmaf(x0, w.z, a0[2]); a0[3] = fmaf(x0, w.w, a0[3]);
      a1[0] = fmaf(x1, w.x, a1[0]); a1[1] = fmaf(x1, w.y, a1[1]);
      a1[2] = fmaf(x1, w.z, a1[2]); a1[3] = fmaf(x1, w.w, a1[3]);
    }
    int r0 = row[eb + e0], r1 = row[eb + e1];
    int t0 = col[eb + e0], t1 = col[eb + e1];
    float4 h0 = *(const float4*)(h + (size_t)r0 * HID + c0);
    float4 h1 = *(const float4*)(h + (size_t)r1 * HID + c0);
    float* p0 = agg + (size_t)t0 * HID + c0;
    float* p1 = agg + (size_t)t1 * HID + c0;
    atomicAdd(p0 + 0, a0[0] * h0.x); atomicAdd(p0 + 1, a0[1] * h0.y);
    atomicAdd(p0 + 2, a0[2] * h0.z); atomicAdd(p0 + 3, a0[3] * h0.w);
    atomicAdd(p1 + 0, a1[0] * h1.x); atomicAdd(p1 + 1, a1[1] * h1.y);
    atomicAdd(p1 + 2, a1[2] * h1.z); atomicAdd(p1 + 3, a1[3] * h1.w);
    __syncthreads();
  }
}

// ---------------- per-layer node update: h += relu(agg@Wd1+bd1)@Wd2+bd2
__global__ __launch_bounds__(256) void k_node(
    const float* __restrict__ agg,
    const float* __restrict__ Wd1, const float* __restrict__ bd1,
    const float* __restrict__ Wd2, const float* __restrict__ bd2,
    float* __restrict__ h) {
  __shared__ float in_s[16][HID];
  __shared__ float r_s[16][HID];
  const int ce = threadIdx.x & 31;
  const int eg = threadIdx.x >> 5;
  const int c0 = ce * 4;
  const int n0 = eg * 2, n1 = n0 + 1;
  for (int tile = blockIdx.x; tile < NN / 16; tile += gridDim.x) {
    const int nb = tile * 16;
    for (int i = threadIdx.x; i < 16 * HID; i += 256) {
      int ln = i >> 7, k = i & 127;
      in_s[ln][k] = agg[(size_t)(nb + ln) * HID + k];
    }
    __syncthreads();
    float a0[4], a1[4];
#pragma unroll
    for (int j = 0; j < 4; ++j) { a0[j] = bd1[c0 + j]; a1[j] = a0[j]; }
    for (int k = 0; k < HID; ++k) {
      float x0 = in_s[n0][k], x1 = in_s[n1][k];
      float4 w = *(const float4*)(Wd1 + (size_t)k * HID + c0);
      a0[0] = fmaf(x0, w.x, a0[0]); a0[1] = fmaf(x0, w.y, a0[1]);
      a0[2] = fmaf(x0, w.z, a0[2]); a0[3] = fmaf(x0, w.w, a0[3]);
      a1[0] = fmaf(x1, w.x, a1[0]); a1[1] = fmaf(x1, w.y, a1[1]);
      a1[2] = fmaf(x1, w.z, a1[2]); a1[3] = fmaf(x1, w.w, a1[3]);
    }
#pragma unroll
    for (int j = 0; j < 4; ++j) {
      r_s[n0][c0 + j] = fmaxf(a0[j], 0.f);
      r_s[n1][c0 + j] = fmaxf(a1[j], 0.f);
    }
    __syncthreads();
#pragma unroll
    for (int j = 0; j < 4; ++j) { a0[j] = bd2[c0 + j]; a1[j] = a0[j]; }
    for (int k = 0; k < HID; ++k) {
      float x0 = r_s[n0][k], x1 = r_s[n1][k];
      float4 w = *(const float4*)(Wd2 + (size_t)k * HID + c0);
      a0[0] = fmaf(x0, w.x, a0[0]); a0[1] = fmaf(x0, w.y, a0[1]);
      a0[2] = fmaf(x0, w.z, a0[2]); a0[3] = fmaf(x0, w.w, a0[3]);
      a1[0] = fmaf(x1, w.x, a1[0]); a1[1] = fmaf(x1, w.y, a1[1]);
      a1[2] = fmaf(x1, w.z, a1[2]); a1[3] = fmaf(x1, w.w, a1[3]);
    }
    float4* hp0 = (float4*)(h + (size_t)(nb + n0) * HID + c0);
    float4* hp1 = (float4*)(h + (size_t)(nb + n1) * HID + c0);
    float4 v0 = *hp0, v1 = *hp1;
    v0.x += a0[0]; v0.y += a0[1]; v0.z += a0[2]; v0.w += a0[3];
    v1.x += a1[0]; v1.y += a1[1]; v1.z += a1[2]; v1.w += a1[3];
    *hp0 = v0; *hp1 = v1;
    __syncthreads();
  }
}

// ---------------- global MLP (G=64, single block)
__global__ __launch_bounds__(128) void k_global(const float* __restrict__ u,
    const float* __restrict__ Wg1, const float* __restrict__ bg1,
    const float* __restrict__ gg1, const float* __restrict__ btg1,
    const float* __restrict__ Wg2, const float* __restrict__ bg2,
    float* __restrict__ u_p) {
  __shared__ float t_s[NGR][HID];  // reused as relu'd values in place
  int c = threadIdx.x;
  for (int g = 0; g < NGR; ++g) {
    float v = bg1[c];
#pragma unroll
    for (int k = 0; k < GD; ++k) v = fmaf(u[(size_t)g * GD + k], Wg1[k * HID + c], v);
    t_s[g][c] = v;
  }
  float sum = 0.f, sq = 0.f;
  for (int g = 0; g < NGR; ++g) { float v = t_s[g][c]; sum += v; sq += v * v; }
  float mean = sum * (1.f / NGR);
  float var = sq * (1.f / NGR) - mean * mean;
  float a = gg1[c] * rsqrtf(var + EPSF);
  float b = btg1[c] - mean * a;
  for (int g = 0; g < NGR; ++g) t_s[g][c] = fmaxf(fmaf(t_s[g][c], a, b), 0.f);
  __syncthreads();
  for (int g = 0; g < NGR; ++g) {
    float acc = bg2[c];
#pragma unroll 8
    for (int k = 0; k < HID; ++k) acc = fmaf(t_s[g][k], Wg2[k * HID + c], acc);
    u_p[(size_t)g * HID + c] = acc;
  }
}

// ---------------- shift head pass 1: t1 = [h, u_p[batch]] @ Ws1 + bs1 (+stats)
__global__ __launch_bounds__(256) void k_shift1(
    const float* __restrict__ h, const float* __restrict__ u_p,
    const int* __restrict__ batch, const float* __restrict__ Ws1,
    const float* __restrict__ bs1, float* __restrict__ t1, float* __restrict__ stats) {
  __shared__ float s_in[16][2 * HID];
  const int c = threadIdx.x & 63;
  const int ng = threadIdx.x >> 6;
  float psum = 0.f, psq = 0.f;
  for (int tile = blockIdx.x; tile < NN / 16; tile += gridDim.x) {
    const int nb = tile * 16;
    for (int i = threadIdx.x; i < 16 * HID; i += 256) {
      int ln = i >> 7, k = i & 127;
      s_in[ln][k] = h[(size_t)(nb + ln) * HID + k];
      s_in[ln][HID + k] = u_p[(size_t)batch[nb + ln] * HID + k];
    }
    __syncthreads();
    float acc[4];
#pragma unroll
    for (int j = 0; j < 4; ++j) acc[j] = bs1[c];
    for (int k = 0; k < 2 * HID; ++k) {
      float w = Ws1[k * SH + c];
#pragma unroll
      for (int j = 0; j < 4; ++j) acc[j] = fmaf(s_in[ng * 4 + j][k], w, acc[j]);
    }
#pragma unroll
    for (int j = 0; j < 4; ++j) {
      t1[(size_t)(nb + ng * 4 + j) * SH + c] = acc[j];
      psum += acc[j]; psq += acc[j] * acc[j];
    }
    __syncthreads();
  }
  __shared__ float rs[256], rq[256];
  rs[threadIdx.x] = psum; rq[threadIdx.x] = psq;
  __syncthreads();
  if (threadIdx.x < 64) {
    int c2 = threadIdx.x;
    atomicAdd(&stats[c2], rs[c2] + rs[c2 + 64] + rs[c2 + 128] + rs[c2 + 192]);
    atomicAdd(&stats[128 + c2], rq[c2] + rq[c2 + 64] + rq[c2 + 128] + rq[c2 + 192]);
  }
}

// ---------------- shift head pass 2: t2 = relu(bn(t1)) @ Ws2 + bs2 (+stats)
__global__ __launch_bounds__(256) void k_shift2(
    const float* __restrict__ t1, float* __restrict__ stats,
    const float* __restrict__ Ws2, const float* __restrict__ bs2,
    float* __restrict__ t2) {
  __shared__ float r_s[16][SH];
  const int c = threadIdx.x & 63;
  const int ng = threadIdx.x >> 6;
  float psum = 0.f, psq = 0.f;
  for (int tile = blockIdx.x; tile < NN / 16; tile += gridDim.x) {
    const int nb = tile * 16;
    for (int i = threadIdx.x; i < 16 * SH; i += 256) {
      int ln = i >> 6, k = i & 63;
      float v = fmaf(t1[(size_t)(nb + ln) * SH + k], stats[256 + k], stats[384 + k]);
      r_s[ln][k] = fmaxf(v, 0.f);
    }
    __syncthreads();
    float acc[4];
#pragma unroll
    for (int j = 0; j < 4; ++j) acc[j] = bs2[c];
    for (int k = 0; k < SH; ++k) {
      float w = Ws2[k * SH + c];
#pragma unroll
      for (int j = 0; j < 4; ++j) acc[j] = fmaf(r_s[ng * 4 + j][k], w, acc[j]);
    }
#pragma unroll
    for (int j = 0; j < 4; ++j) {
      t2[(size_t)(nb + ng * 4 + j) * SH + c] = acc[j];
      psum += acc[j]; psq += acc[j] * acc[j];
    }
    __syncthreads();
  }
  __shared__ float rs[256], rq[256];
  rs[threadIdx.x] = psum; rq[threadIdx.x] = psq;
  __syncthreads();
  if (threadIdx.x < 64) {
    int c2 = threadIdx.x;
    atomicAdd(&stats[c2], rs[c2] + rs[c2 + 64] + rs[c2 + 128] + rs[c2 + 192]);
    atomicAdd(&stats[128 + c2], rq[c2] + rq[c2 + 64] + rq[c2 + 128] + rq[c2 + 192]);
  }
}

// ---------------- shift head pass 3: shifts = relu(bn(t2)) @ Ws3 + bs3
__global__ __launch_bounds__(256) void k_shift3(
    const float* __restrict__ t2, const float* __restrict__ stats,
    const float* __restrict__ Ws3, const float* __restrict__ bs3,
    float* __restrict__ shifts) {
  int lane = threadIdx.x & 63;
  int n = blockIdx.x * 4 + (threadIdx.x >> 6);
  if (n >= NN) return;
  float a = stats[256 + lane], b = stats[384 + lane];
  float r = fmaxf(fmaf(t2[(size_t)n * SH + lane], a, b), 0.f);
  float v = r * Ws3[lane];
#pragma unroll
  for (int off = 32; off; off >>= 1) v += __shfl_down(v, off);
  if (lane == 0) shifts[n] = v + bs3[0];
}

extern "C" void kernel_launch(void* const* d_in, const int* in_sizes, int n_in,
                              void* d_out, int out_size, void* d_ws, size_t ws_size,
                              hipStream_t stream) {
  const float* x     = (const float*)d_in[0];
  const int*   ei    = (const int*)d_in[1];
  const float* eattr = (const float*)d_in[2];
  const int*   batch = (const int*)d_in[3];
  const float* u     = (const float*)d_in[4];
  const float* We1 = (const float*)d_in[5];  const float* be1 = (const float*)d_in[6];
  const float* ge1 = (const float*)d_in[7];  const float* bte1 = (const float*)d_in[8];
  const float* We2 = (const float*)d_in[9];  const float* be2 = (const float*)d_in[10];
  const float* Wf1 = (const float*)d_in[11]; const float* bf1 = (const float*)d_in[12];
  const float* Wf2 = (const float*)d_in[13]; const float* bf2 = (const float*)d_in[14];
  const float* Wd1 = (const float*)d_in[15]; const float* bd1 = (const float*)d_in[16];
  const float* Wd2 = (const float*)d_in[17]; const float* bd2 = (const float*)d_in[18];
  const float* Wg1 = (const float*)d_in[19]; const float* bg1 = (const float*)d_in[20];
  const float* gg1 = (const float*)d_in[21]; const float* btg1 = (const float*)d_in[22];
  const float* Wg2 = (const float*)d_in[23]; const float* bg2 = (const float*)d_in[24];
  const float* Ws1 = (const float*)d_in[25]; const float* bs1 = (const float*)d_in[26];
  const float* gs1 = (const float*)d_in[27]; const float* bts1 = (const float*)d_in[28];
  const float* Ws2 = (const float*)d_in[29]; const float* bs2 = (const float*)d_in[30];
  const float* gs2 = (const float*)d_in[31]; const float* bts2 = (const float*)d_in[32];
  const float* Ws3 = (const float*)d_in[33]; const float* bs3 = (const float*)d_in[34];

  float* out    = (float*)d_out;
  float* shifts = out;                    // [NN]
  float* h      = out + NN;               // [NN,HID]
  float* ea     = out + NN + NN * HID;    // [NE,NG]
  float* u_p    = out + NN + NN * HID + (size_t)NE * NG;  // [NGR,HID]

  float* stats = (float*)d_ws;            // 512 floats
  float* buf1  = stats + 512;             // NN*HID floats (t / agg / t1+t2)
  float* t1 = buf1;                       // [NN,SH]
  float* t2 = buf1 + (size_t)NN * SH;     // [NN,SH]

  const int* row = ei;        // source j
  const int* col = ei + NE;   // target i

  const int* rowp = row; const int* colp = col;

  // node encoder
  hipMemsetAsync(stats, 0, 256 * sizeof(float), stream);
  k_enc1<<<512, 256, 0, stream>>>(x, We1, be1, buf1, stats);
  k_bn_fin<<<1, 128, 0, stream>>>(ge1, bte1, stats, 128, 1.f / NN);
  k_enc2<<<2048, 128, 0, stream>>>(buf1, stats, We2, be2, h);

  // gaussian smearing
  k_smear<<<(NE * NG + 255) / 256, 256, 0, stream>>>(eattr, ea);

  // interaction layers
  for (int l = 0; l < NL; ++l) {
    hipMemsetAsync(buf1, 0, (size_t)NN * HID * sizeof(float), stream);
    k_edge<<<2048, 256, 0, stream>>>(ea, h, rowp, colp,
                                     Wf1 + (size_t)l * NG * NF, bf1 + (size_t)l * NF,
                                     Wf2 + (size_t)l * NF * NF, bf2 + (size_t)l * NF,
                                     buf1);
    k_node<<<1024, 256, 0, stream>>>(buf1,
                                     Wd1 + (size_t)l * HID * HID, bd1 + (size_t)l * HID,
                                     Wd2 + (size_t)l * HID * HID, bd2 + (size_t)l * HID,
                                     h);
  }

  // global MLP
  k_global<<<1, 128, 0, stream>>>(u, Wg1, bg1, gg1, btg1, Wg2, bg2, u_p);

  // shift head
  hipMemsetAsync(stats, 0, 256 * sizeof(float), stream);
  k_shift1<<<1024, 256, 0, stream>>>(h, u_p, batch, Ws1, bs1, t1, stats);
  k_bn_fin<<<1, 128, 0, stream>>>(gs1, bts1, stats, 64, 1.f / NN);
  hipMemsetAsync(stats, 0, 256 * sizeof(float), stream);
  k_shift2<<<1024, 256, 0, stream>>>(t1, stats, Ws2, bs2, t2);
  k_bn_fin<<<1, 128, 0, stream>>>(gs2, bts2, stats, 64, 1.f / NN);
  k_shift3<<<(NN + 3) / 4, 256, 0, stream>>>(t2, stats, Ws3, bs3, shifts);
}